// Round 1
// baseline (203.390 us; speedup 1.0000x reference)
//
#include <hip/hip_runtime.h>
#include <stdint.h>
#include <stddef.h>

// Reference collapse:
//   softmax over k sums to 1 and the einsum applies it pointwise to v,
//   so out = conv1x1(conv1x1(x, W_v, b_v), W_proj, b_proj)
//          = (W_proj @ W_v) @ x  + (W_proj @ b_v + b_proj)
// One 192x192 bf16-MFMA GEMM over 8*16384 pixels. Memory-bound (~201 MB).

#define CDIM 192
#define HWPX 16384
#define LDS_STRIDE 200  // 192 + 8 pad (ushorts); 2-way LDS bank aliasing = free

typedef __attribute__((ext_vector_type(8))) short short8;
typedef __attribute__((ext_vector_type(4))) float floatx4;
typedef __attribute__((ext_vector_type(4))) unsigned short ushort4_t;

__device__ __forceinline__ unsigned short f2bf(float f) {
    union { float f; unsigned int u; } v; v.f = f;
    unsigned int r = (v.u + 0x7FFFu + ((v.u >> 16) & 1u)) >> 16;  // RTNE
    return (unsigned short)r;
}

// ---- prep: M = W_proj @ W_v (bf16), bias = W_proj @ b_v + b_proj ----
__global__ __launch_bounds__(192) void prep_kernel(
    const float* __restrict__ w_qkv, const float* __restrict__ b_qkv,
    const float* __restrict__ w_proj, const float* __restrict__ b_proj,
    unsigned short* __restrict__ Mb, float* __restrict__ bias)
{
    const int o = blockIdx.x, c = threadIdx.x;
    const float* wpr = w_proj + o * CDIM;
    const float* wv  = w_qkv + 2 * CDIM * CDIM;  // v-rows of w_qkv
    float acc = 0.f;
    #pragma unroll 32
    for (int k = 0; k < CDIM; ++k)
        acc = fmaf(wpr[k], wv[k * CDIM + c], acc);
    Mb[o * CDIM + c] = f2bf(acc);

    __shared__ float red[CDIM];
    red[c] = wpr[c] * b_qkv[2 * CDIM + c];
    __syncthreads();
    if (c < 64) {
        float v = red[c] + red[c + 64] + red[c + 128];
        #pragma unroll
        for (int off = 32; off > 0; off >>= 1) v += __shfl_down(v, off);
        if (c == 0) bias[o] = v + b_proj[o];
    }
}

// ---- main: out[b, :, p0:p0+64] = M @ x[b, :, p0:p0+64] + bias ----
__global__ __launch_bounds__(256, 2) void fused_kernel(
    const float* __restrict__ x,
    const unsigned short* __restrict__ Mb,
    const float* __restrict__ bias,
    float* __restrict__ out)
{
    __shared__ unsigned short Xl[64 * LDS_STRIDE];  // 25.6 KB: x tile, bf16, [p][c]

    const int tid = threadIdx.x;
    const int bid = blockIdx.x;
    const int b   = bid >> 8;          // 256 pixel-tiles per batch
    const int p0  = (bid & 255) << 6;  // 64 pixels per tile

    const int lane = tid & 63;
    const int w    = tid >> 6;    // wave 0..3
    const int n    = lane & 15;   // MFMA n / m-lane index
    const int q    = lane >> 4;   // MFMA quad

    // stage x tile (192 c x 64 p fp32) -> LDS bf16 transposed [p][c]
    const float* xb = x + (size_t)b * CDIM * HWPX + p0;
    #pragma unroll
    for (int it = 0; it < 3; ++it) {
        const int slot = it * 256 + tid;   // 768 slots = 48 c-groups x 16 p-groups
        const int p4   = slot & 15;        // pixel group (4 px)
        const int cg4  = slot >> 4;        // channel group (4 ch), 0..47
        const float* src = xb + (size_t)(cg4 * 4) * HWPX + p4 * 4;
        floatx4 f0 = *(const floatx4*)(src);
        floatx4 f1 = *(const floatx4*)(src + HWPX);
        floatx4 f2 = *(const floatx4*)(src + 2 * HWPX);
        floatx4 f3 = *(const floatx4*)(src + 3 * HWPX);
        #pragma unroll
        for (int i = 0; i < 4; ++i) {
            ushort4_t v4;
            v4.x = f2bf(f0[i]); v4.y = f2bf(f1[i]);
            v4.z = f2bf(f2[i]); v4.w = f2bf(f3[i]);
            *(ushort4_t*)&Xl[(p4 * 4 + i) * LDS_STRIDE + cg4 * 4] = v4;
        }
    }
    __syncthreads();

    floatx4 acc[3][4];
    #pragma unroll
    for (int t = 0; t < 3; ++t)
        #pragma unroll
        for (int pt = 0; pt < 4; ++pt)
            acc[t][pt] = (floatx4){0.f, 0.f, 0.f, 0.f};

    // wave w covers output channels [w*48, w*48+48): 3 o-tiles of 16
    #pragma unroll
    for (int t = 0; t < 3; ++t) {
        const int ot = w * 3 + t;
        short8 a[6];
        const unsigned short* arow = Mb + (ot * 16 + n) * CDIM + q * 8;
        #pragma unroll
        for (int ks = 0; ks < 6; ++ks)        // A[m=lane&15][k=quad*8+j]
            a[ks] = *(const short8*)(arow + ks * 32);
        #pragma unroll
        for (int pt = 0; pt < 4; ++pt) {
            const unsigned short* brow = &Xl[(pt * 16 + n) * LDS_STRIDE + q * 8];
            #pragma unroll
            for (int ks = 0; ks < 6; ++ks) {  // B[k=quad*8+j][n=lane&15]
                short8 bfr = *(const short8*)(brow + ks * 32);
                acc[t][pt] = __builtin_amdgcn_mfma_f32_16x16x32_bf16(
                    a[ks], bfr, acc[t][pt], 0, 0, 0);
            }
        }
    }

    // store: D row = q*4 + r, col = n
    float* ob = out + (size_t)b * CDIM * HWPX + p0;
    #pragma unroll
    for (int t = 0; t < 3; ++t) {
        const int ot = w * 3 + t;
        #pragma unroll
        for (int r = 0; r < 4; ++r) {
            const int o = ot * 16 + q * 4 + r;
            const float bo = bias[o];
            float* orow = ob + (size_t)o * HWPX + n;
            #pragma unroll
            for (int pt = 0; pt < 4; ++pt)
                orow[pt * 16] = acc[t][pt][r] + bo;
        }
    }
}

extern "C" void kernel_launch(void* const* d_in, const int* in_sizes, int n_in,
                              void* d_out, int out_size, void* d_ws, size_t ws_size,
                              hipStream_t stream) {
    const float* x      = (const float*)d_in[0];
    const float* w_qkv  = (const float*)d_in[1];
    const float* b_qkv  = (const float*)d_in[2];
    // d_in[3] = w_attn, d_in[4] = b_attn: mathematically unused (softmax sums to 1)
    const float* w_proj = (const float*)d_in[5];
    const float* b_proj = (const float*)d_in[6];
    float* out = (float*)d_out;

    unsigned short* Mb = (unsigned short*)d_ws;                       // 192*192 bf16
    float* bias = (float*)((char*)d_ws + CDIM * CDIM * sizeof(unsigned short));

    const int B = in_sizes[0] / (CDIM * HWPX);  // 8

    prep_kernel<<<CDIM, CDIM, 0, stream>>>(w_qkv, b_qkv, w_proj, b_proj, Mb, bias);
    fused_kernel<<<B * 256, 256, 0, stream>>>(x, Mb, bias, out);
}